// Round 1
// baseline (451.909 us; speedup 1.0000x reference)
//
#include <hip/hip_runtime.h>
#include <hip/hip_bf16.h>
#include <math.h>

#define D_INNER 8192
#define D_MODEL 4096
#define DT_RANK 8
#define D_STATE 16

// ---------------------------------------------------------------------------
// K1: xz = W_in @ x  (16384 rows x 4096 cols).
// One wave (64 lanes) per row, 4 waves per block. Epilogue fuses the depthwise
// conv + SiLU for rows < D_INNER (x branch) and SiLU for rows >= D_INNER (z).
// ---------------------------------------------------------------------------
__global__ __launch_bounds__(256) void gemv_in_kernel(
    const float* __restrict__ W_in, const float* __restrict__ x,
    const float* __restrict__ conv_buffer, const float* __restrict__ conv_w,
    const float* __restrict__ conv_b,
    float* __restrict__ x_conv, float* __restrict__ silu_z) {
  const int wave = threadIdx.x >> 6;
  const int lane = threadIdx.x & 63;
  const int row = blockIdx.x * 4 + wave;           // grid = 4096 blocks
  const float4* __restrict__ Wr = (const float4*)(W_in + (size_t)row * D_MODEL);
  const float4* __restrict__ x4 = (const float4*)x;

  float acc = 0.f;
#pragma unroll 8
  for (int it = 0; it < 16; ++it) {                 // 1024 float4 / 64 lanes
    float4 w = Wr[lane + it * 64];
    float4 v = x4[lane + it * 64];
    acc += w.x * v.x + w.y * v.y + w.z * v.z + w.w * v.w;
  }
#pragma unroll
  for (int off = 32; off; off >>= 1) acc += __shfl_down(acc, off, 64);

  if (lane == 0) {
    if (row < D_INNER) {
      // conv_in = [buf1, buf2, xb, xb] . conv_w + conv_b, then SiLU
      float pre = conv_buffer[row * 3 + 1] * conv_w[row * 4 + 0]
                + conv_buffer[row * 3 + 2] * conv_w[row * 4 + 1]
                + acc * (conv_w[row * 4 + 2] + conv_w[row * 4 + 3])
                + conv_b[row];
      x_conv[row] = pre / (1.f + __expf(-pre));
    } else {
      const int i = row - D_INNER;
      silu_z[i] = acc / (1.f + __expf(-acc));
    }
  }
}

// ---------------------------------------------------------------------------
// K2: xp = W_xp @ x_conv  (40 rows x 8192 cols). One block per output row.
// ---------------------------------------------------------------------------
__global__ __launch_bounds__(256) void gemv_xp_kernel(
    const float* __restrict__ W_xp, const float* __restrict__ x_conv,
    float* __restrict__ xp) {
  const int j = blockIdx.x;                         // 0..39
  const float4* __restrict__ Wr = (const float4*)(W_xp + (size_t)j * D_INNER);
  const float4* __restrict__ xc4 = (const float4*)x_conv;

  float acc = 0.f;
#pragma unroll
  for (int it = 0; it < 8; ++it) {                  // 2048 float4 / 256 thr
    float4 w = Wr[threadIdx.x + it * 256];
    float4 v = xc4[threadIdx.x + it * 256];
    acc += w.x * v.x + w.y * v.y + w.z * v.z + w.w * v.w;
  }
#pragma unroll
  for (int off = 32; off; off >>= 1) acc += __shfl_down(acc, off, 64);

  __shared__ float part[4];
  if ((threadIdx.x & 63) == 0) part[threadIdx.x >> 6] = acc;
  __syncthreads();
  if (threadIdx.x == 0) xp[j] = part[0] + part[1] + part[2] + part[3];
}

// ---------------------------------------------------------------------------
// K3: per-channel SSM cell. dt = softplus(W_dt@xp[:8] + b_dt); state update;
// y = (h . C) + D*x_conv, gated by silu(z). new_h written straight to d_out.
// ---------------------------------------------------------------------------
__global__ __launch_bounds__(256) void cell_kernel(
    const float* __restrict__ W_dt, const float* __restrict__ b_dt,
    const float* __restrict__ A_log, const float* __restrict__ ssm_state,
    const float* __restrict__ D_param, const float* __restrict__ x_conv,
    const float* __restrict__ silu_z, const float* __restrict__ xp,
    float* __restrict__ new_h, float* __restrict__ y) {
  const int i = blockIdx.x * blockDim.x + threadIdx.x;
  if (i >= D_INNER) return;

  float d = b_dt[i];
#pragma unroll
  for (int j = 0; j < DT_RANK; ++j) d += W_dt[i * DT_RANK + j] * xp[j];
  // stable softplus
  const float dt = (d > 20.f) ? d : log1pf(__expf(d));

  const float xc = x_conv[i];
  float y_acc = 0.f;
#pragma unroll
  for (int s = 0; s < D_STATE; ++s) {
    const float A    = -__expf(A_log[i * D_STATE + s]);
    const float Abar = __expf(dt * A);
    const float h    = Abar * ssm_state[i * D_STATE + s]
                     + dt * xp[DT_RANK + s] * xc;
    new_h[i * D_STATE + s] = h;
    y_acc += h * xp[DT_RANK + D_STATE + s];
  }
  y_acc += D_param[i] * xc;
  y[i] = y_acc * silu_z[i];
}

// ---------------------------------------------------------------------------
// K4: out = W_out @ y  (4096 rows x 8192 cols). One wave per row.
// ---------------------------------------------------------------------------
__global__ __launch_bounds__(256) void gemv_out_kernel(
    const float* __restrict__ W_out, const float* __restrict__ y,
    float* __restrict__ out) {
  const int wave = threadIdx.x >> 6;
  const int lane = threadIdx.x & 63;
  const int row = blockIdx.x * 4 + wave;            // grid = 1024 blocks
  const float4* __restrict__ Wr = (const float4*)(W_out + (size_t)row * D_INNER);
  const float4* __restrict__ y4 = (const float4*)y;

  float acc = 0.f;
#pragma unroll 8
  for (int it = 0; it < 32; ++it) {                 // 2048 float4 / 64 lanes
    float4 w = Wr[lane + it * 64];
    float4 v = y4[lane + it * 64];
    acc += w.x * v.x + w.y * v.y + w.z * v.z + w.w * v.w;
  }
#pragma unroll
  for (int off = 32; off; off >>= 1) acc += __shfl_down(acc, off, 64);
  if (lane == 0) out[row] = acc;
}

extern "C" void kernel_launch(void* const* d_in, const int* in_sizes, int n_in,
                              void* d_out, int out_size, void* d_ws, size_t ws_size,
                              hipStream_t stream) {
  const float* x           = (const float*)d_in[0];
  const float* ssm_state   = (const float*)d_in[1];
  const float* conv_buffer = (const float*)d_in[2];
  const float* W_in        = (const float*)d_in[3];
  const float* conv_w      = (const float*)d_in[4];
  const float* conv_b      = (const float*)d_in[5];
  const float* W_xp        = (const float*)d_in[6];
  const float* W_dt        = (const float*)d_in[7];
  const float* b_dt        = (const float*)d_in[8];
  const float* A_log       = (const float*)d_in[9];
  const float* D_param     = (const float*)d_in[10];
  const float* W_out       = (const float*)d_in[11];

  float* out   = (float*)d_out;            // [0, 4096): out
  float* new_h = (float*)d_out + D_MODEL;  // [4096, 4096+131072): new_h

  float* ws     = (float*)d_ws;
  float* x_conv = ws;                      // 8192
  float* silu_z = ws + 8192;               // 8192
  float* xp     = ws + 16384;              // 40
  float* y      = ws + 16448;              // 8192

  gemv_in_kernel<<<(2 * D_INNER) / 4, 256, 0, stream>>>(
      W_in, x, conv_buffer, conv_w, conv_b, x_conv, silu_z);
  gemv_xp_kernel<<<DT_RANK + 2 * D_STATE, 256, 0, stream>>>(W_xp, x_conv, xp);
  cell_kernel<<<D_INNER / 256, 256, 0, stream>>>(
      W_dt, b_dt, A_log, ssm_state, D_param, x_conv, silu_z, xp, new_h, y);
  gemv_out_kernel<<<D_MODEL / 4, 256, 0, stream>>>(W_out, y, out);
}